// Round 1
// baseline (117.411 us; speedup 1.0000x reference)
//
#include <hip/hip_runtime.h>
#include <cstdint>
#include <cstddef>

#define NN 8192
#define INF 512
#define OUTF 64
#define ALPHA 0.2f

typedef short bf16x8 __attribute__((ext_vector_type(8)));
typedef float f32x4 __attribute__((ext_vector_type(4)));

static __device__ inline unsigned short f2bf(float f) {
    unsigned u = __builtin_bit_cast(unsigned, f);
    unsigned r = (u + 0x7FFFu + ((u >> 16) & 1u)) >> 16;
    return (unsigned short)r;
}

// ---------------------------------------------------------------------------
// Kernel 1: Wh = x @ W (fp32), then:
//   WhbT[c][i] = bf16(Wh[i][c])   (transposed bf16 copy for MFMA A-operand)
//   s1[i] = Wh[i][:] . a[0:64],  s2[i] = Wh[i][:] . a[64:128]
// 512 blocks x 256 threads; each block computes 16 rows of Wh.
// ---------------------------------------------------------------------------
__global__ __launch_bounds__(256) void k1_gemm(
    const float* __restrict__ x, const float* __restrict__ W,
    const float* __restrict__ a, unsigned short* __restrict__ WhbT,
    float* __restrict__ s1, float* __restrict__ s2)
{
    __shared__ float xs[16][512];   // 32 KB
    const int tid = threadIdx.x;
    const int i0  = blockIdx.x * 16;

    // stage x tile: 16 rows x 512 f32 = 2048 float4
    #pragma unroll
    for (int k = 0; k < 8; ++k) {
        int f  = tid + 256 * k;
        int r  = f >> 7;
        int c4 = f & 127;
        *(float4*)&xs[r][c4 * 4] =
            *(const float4*)&x[(size_t)(i0 + r) * INF + c4 * 4];
    }
    __syncthreads();

    const int w = tid >> 6;    // wave 0..3 -> rows 4w..4w+3
    const int c = tid & 63;    // output column
    float acc[4] = {0.f, 0.f, 0.f, 0.f};
    const float* Wc = W + c;

    for (int kk = 0; kk < 128; ++kk) {
        float4 xv[4];
        #pragma unroll
        for (int q = 0; q < 4; ++q)
            xv[q] = *(const float4*)&xs[4 * w + q][kk * 4];
        float wv[4];
        #pragma unroll
        for (int e = 0; e < 4; ++e)
            wv[e] = Wc[(kk * 4 + e) * OUTF];
        #pragma unroll
        for (int q = 0; q < 4; ++q) {
            acc[q] = fmaf(xv[q].x, wv[0], acc[q]);
            acc[q] = fmaf(xv[q].y, wv[1], acc[q]);
            acc[q] = fmaf(xv[q].z, wv[2], acc[q]);
            acc[q] = fmaf(xv[q].w, wv[3], acc[q]);
        }
    }

    // s1/s2 wave reductions (64 lanes, one row per reduction)
    const float a1c = a[c];
    const float a2c = a[64 + c];
    #pragma unroll
    for (int q = 0; q < 4; ++q) {
        float v1 = acc[q] * a1c;
        float v2 = acc[q] * a2c;
        #pragma unroll
        for (int m = 32; m; m >>= 1) {
            v1 += __shfl_xor(v1, m, 64);
            v2 += __shfl_xor(v2, m, 64);
        }
        if (c == 0) {
            s1[i0 + 4 * w + q] = v1;
            s2[i0 + 4 * w + q] = v2;
        }
    }

    // transposed bf16 store: WhbT[c][i0+4w+q], 4 consecutive j -> one 8B store
    ushort4 pk;
    pk.x = f2bf(acc[0]); pk.y = f2bf(acc[1]);
    pk.z = f2bf(acc[2]); pk.w = f2bf(acc[3]);
    *(ushort4*)&WhbT[(size_t)c * NN + i0 + 4 * w] = pk;
}

// ---------------------------------------------------------------------------
// Kernel 2: fused masked-softmax attention (unshifted softmax, one adj pass).
//   p[i][j] = adj ? exp(leakyrelu(s1[i]+s2[j])) : 0
//   Opart   = P @ Wh  (bf16 MFMA, computed as out^T = WhbT * P^T)
//   lpart   = rowsum(P)
// Grid: 1024 blocks = 512 row-tiles (16 rows) x 2 j-splits (4096 j each).
// ---------------------------------------------------------------------------
__global__ __launch_bounds__(256) void k2_attn(
    const int* __restrict__ adj, const unsigned short* __restrict__ WhbT,
    const float* __restrict__ s1g, const float* __restrict__ s2g,
    float* __restrict__ Opart, float* __restrict__ lpart)
{
    __shared__ unsigned short p_lds[16][80];   // padded: stride 160B, 16B-aligned rows

    const int tid    = threadIdx.x;
    const int bid    = blockIdx.x;
    const int i0     = (bid & 511) * 16;
    const int split  = bid >> 9;               // 0 or 1
    const int jbase  = split * 4096;

    // phase-A layout: 8 row-groups x 32 lanes, 2 adjacent j per lane
    const int lane32 = tid & 31;
    const int rg     = tid >> 5;               // 0..7 -> rows rg, rg+8
    const int jj2    = lane32 * 2;
    const float s1v0 = s1g[i0 + rg];
    const float s1v1 = s1g[i0 + rg + 8];
    float lac0 = 0.f, lac1 = 0.f;

    // MFMA layout: wave w owns output cols n0..n0+15 (out^T: A=WhbT, B=P^T)
    const int l    = tid & 63;
    const int w    = tid >> 6;
    const int n0   = w * 16;
    const int kgrp = l >> 4;
    const unsigned short* Abase = WhbT + (size_t)(n0 + (l & 15)) * NN + kgrp * 8;
    const unsigned short* Bbase = &p_lds[l & 15][kgrp * 8];
    f32x4 acc = {0.f, 0.f, 0.f, 0.f};

    // prefetch tile 0
    const size_t adjr0 = (size_t)(i0 + rg) * NN + jbase + jj2;
    const size_t adjr1 = adjr0 + (size_t)8 * NN;
    int2   av0 = *(const int2*)&adj[adjr0];
    int2   av1 = *(const int2*)&adj[adjr1];
    float2 s2v = *(const float2*)&s2g[jbase + jj2];

    for (int t = 0; t < 64; ++t) {
        const int j0 = jbase + t * 64;

        // A-fragments for this tile (independent of LDS; in flight over phase A)
        bf16x8 A0 = *(const bf16x8*)(Abase + j0);
        bf16x8 A1 = *(const bf16x8*)(Abase + j0 + 32);

        // phase A: scores -> P tile in LDS
        float e, p00, p01, p10, p11;
        e = s1v0 + s2v.x; e = e > 0.f ? e : ALPHA * e; p00 = av0.x ? __expf(e) : 0.f;
        e = s1v0 + s2v.y; e = e > 0.f ? e : ALPHA * e; p01 = av0.y ? __expf(e) : 0.f;
        e = s1v1 + s2v.x; e = e > 0.f ? e : ALPHA * e; p10 = av1.x ? __expf(e) : 0.f;
        e = s1v1 + s2v.y; e = e > 0.f ? e : ALPHA * e; p11 = av1.y ? __expf(e) : 0.f;
        lac0 += p00 + p01;
        lac1 += p10 + p11;
        unsigned pk0 = (unsigned)f2bf(p00) | ((unsigned)f2bf(p01) << 16);
        unsigned pk1 = (unsigned)f2bf(p10) | ((unsigned)f2bf(p11) << 16);
        *(unsigned*)&p_lds[rg][jj2]     = pk0;
        *(unsigned*)&p_lds[rg + 8][jj2] = pk1;

        // prefetch next tile's adj / s2
        if (t < 63) {
            av0 = *(const int2*)&adj[adjr0 + (size_t)(t + 1) * 64];
            av1 = *(const int2*)&adj[adjr1 + (size_t)(t + 1) * 64];
            s2v = *(const float2*)&s2g[j0 + 64 + jj2];
        }
        __syncthreads();

        // phase B: out^T tile += WhbT-tile * P^T-tile
        bf16x8 B0 = *(const bf16x8*)(Bbase);
        bf16x8 B1 = *(const bf16x8*)(Bbase + 32);
        acc = __builtin_amdgcn_mfma_f32_16x16x32_bf16(A0, B0, acc, 0, 0, 0);
        acc = __builtin_amdgcn_mfma_f32_16x16x32_bf16(A1, B1, acc, 0, 0, 0);
        __syncthreads();
    }

    // reduce row-sums over the 32 lanes of each half-wave row-group
    #pragma unroll
    for (int m = 16; m; m >>= 1) {
        lac0 += __shfl_xor(lac0, m, 64);
        lac1 += __shfl_xor(lac1, m, 64);
    }
    if (lane32 == 0) {
        lpart[(size_t)split * NN + i0 + rg]     = lac0;
        lpart[(size_t)split * NN + i0 + rg + 8] = lac1;
    }

    // write numerator partial: C layout col=lane&15 (i-local), row=(lane>>4)*4+q (n-local)
    const int ii = l & 15;
    const int nn = (l >> 4) * 4;
    float4 o;
    o.x = acc[0]; o.y = acc[1]; o.z = acc[2]; o.w = acc[3];
    *(float4*)&Opart[((size_t)split * NN + i0 + ii) * OUTF + n0 + nn] = o;
}

// ---------------------------------------------------------------------------
// Kernel 3: combine j-split partials and normalize.
// ---------------------------------------------------------------------------
__global__ __launch_bounds__(256) void k3_combine(
    const float* __restrict__ Opart, const float* __restrict__ lpart,
    float* __restrict__ out)
{
    const int f4 = blockIdx.x * 256 + threadIdx.x;   // 0..131071
    const int i  = f4 >> 4;
    float4 o0 = *(const float4*)&Opart[(size_t)f4 * 4];
    float4 o1 = *(const float4*)&Opart[(size_t)NN * OUTF + (size_t)f4 * 4];
    float inv = 1.0f / (lpart[i] + lpart[NN + i]);
    float4 r;
    r.x = (o0.x + o1.x) * inv;
    r.y = (o0.y + o1.y) * inv;
    r.z = (o0.z + o1.z) * inv;
    r.w = (o0.w + o1.w) * inv;
    *(float4*)&out[(size_t)f4 * 4] = r;
}

extern "C" void kernel_launch(void* const* d_in, const int* in_sizes, int n_in,
                              void* d_out, int out_size, void* d_ws, size_t ws_size,
                              hipStream_t stream) {
    const float* x   = (const float*)d_in[0];
    const int*   adj = (const int*)d_in[1];
    const float* W   = (const float*)d_in[2];
    const float* a   = (const float*)d_in[3];
    float* out = (float*)d_out;

    char* ws = (char*)d_ws;
    unsigned short* WhbT = (unsigned short*)ws;                    // 1 MB
    float* s1    = (float*)(ws + (1 << 20));                       // 32 KB
    float* s2    = (float*)(ws + (1 << 20) + 32768);               // 32 KB
    float* lpart = (float*)(ws + (1 << 20) + 65536);               // 64 KB
    float* Opart = (float*)(ws + (1 << 20) + 65536 + 65536);       // 4 MB

    k1_gemm<<<512, 256, 0, stream>>>(x, W, a, WhbT, s1, s2);
    k2_attn<<<1024, 256, 0, stream>>>(adj, WhbT, s1, s2, Opart, lpart);
    k3_combine<<<512, 256, 0, stream>>>(Opart, lpart, out);
}

// Round 2
// 107.233 us; speedup vs baseline: 1.0949x; 1.0949x over previous
//
#include <hip/hip_runtime.h>
#include <cstdint>
#include <cstddef>

#define NN 8192
#define INF 512
#define OUTF 64
#define ALPHA 0.2f

typedef short bf16x8 __attribute__((ext_vector_type(8)));
typedef float f32x4 __attribute__((ext_vector_type(4)));

static __device__ inline unsigned short f2bf(float f) {
    unsigned u = __builtin_bit_cast(unsigned, f);
    unsigned r = (u + 0x7FFFu + ((u >> 16) & 1u)) >> 16;
    return (unsigned short)r;
}

// ---------------------------------------------------------------------------
// Kernel 1: Wh = x @ W (fp32), then:
//   WhbT[c][i] = bf16(Wh[i][c])   (transposed bf16 copy for MFMA A-operand)
//   s1[i] = Wh[i][:] . a[0:64],  s2[i] = Wh[i][:] . a[64:128]
// 512 blocks x 256 threads; each block computes 16 rows of Wh.
// ---------------------------------------------------------------------------
__global__ __launch_bounds__(256) void k1_gemm(
    const float* __restrict__ x, const float* __restrict__ W,
    const float* __restrict__ a, unsigned short* __restrict__ WhbT,
    float* __restrict__ s1, float* __restrict__ s2)
{
    __shared__ float xs[16][512];   // 32 KB
    const int tid = threadIdx.x;
    const int i0  = blockIdx.x * 16;

    // stage x tile: 16 rows x 512 f32 = 2048 float4
    #pragma unroll
    for (int k = 0; k < 8; ++k) {
        int f  = tid + 256 * k;
        int r  = f >> 7;
        int c4 = f & 127;
        *(float4*)&xs[r][c4 * 4] =
            *(const float4*)&x[(size_t)(i0 + r) * INF + c4 * 4];
    }
    __syncthreads();

    const int w = tid >> 6;    // wave 0..3 -> rows 4w..4w+3
    const int c = tid & 63;    // output column
    float acc[4] = {0.f, 0.f, 0.f, 0.f};
    const float* Wc = W + c;

    for (int kk = 0; kk < 128; ++kk) {
        float4 xv[4];
        #pragma unroll
        for (int q = 0; q < 4; ++q)
            xv[q] = *(const float4*)&xs[4 * w + q][kk * 4];
        float wv[4];
        #pragma unroll
        for (int e = 0; e < 4; ++e)
            wv[e] = Wc[(kk * 4 + e) * OUTF];
        #pragma unroll
        for (int q = 0; q < 4; ++q) {
            acc[q] = fmaf(xv[q].x, wv[0], acc[q]);
            acc[q] = fmaf(xv[q].y, wv[1], acc[q]);
            acc[q] = fmaf(xv[q].z, wv[2], acc[q]);
            acc[q] = fmaf(xv[q].w, wv[3], acc[q]);
        }
    }

    // s1/s2 wave reductions (64 lanes, one row per reduction)
    const float a1c = a[c];
    const float a2c = a[64 + c];
    #pragma unroll
    for (int q = 0; q < 4; ++q) {
        float v1 = acc[q] * a1c;
        float v2 = acc[q] * a2c;
        #pragma unroll
        for (int m = 32; m; m >>= 1) {
            v1 += __shfl_xor(v1, m, 64);
            v2 += __shfl_xor(v2, m, 64);
        }
        if (c == 0) {
            s1[i0 + 4 * w + q] = v1;
            s2[i0 + 4 * w + q] = v2;
        }
    }

    // transposed bf16 store: WhbT[c][i0+4w+q], 4 consecutive j -> one 8B store
    ushort4 pk;
    pk.x = f2bf(acc[0]); pk.y = f2bf(acc[1]);
    pk.z = f2bf(acc[2]); pk.w = f2bf(acc[3]);
    *(ushort4*)&WhbT[(size_t)c * NN + i0 + 4 * w] = pk;
}

// ---------------------------------------------------------------------------
// Kernel 2: fused masked-softmax attention (unshifted softmax, one adj pass).
//   p[i][j] = adj ? exp(leakyrelu(s1[i]+s2[j])) : 0
//   Opart   = P @ Wh  (bf16 MFMA, computed as out^T = WhbT * P^T)
//   lpart   = rowsum(P)
// Grid: 1024 blocks = 512 row-tiles (16 rows) x 2 j-splits (4096 j each).
// Pipeline: 32 iters of 128-j tiles; double-buffered P in LDS (1 barrier per
// tile); adj/s2 prefetched 2 tiles ahead in named register slots.
// ---------------------------------------------------------------------------
__global__ __launch_bounds__(256) void k2_attn(
    const int* __restrict__ adj, const unsigned short* __restrict__ WhbT,
    const float* __restrict__ s1g, const float* __restrict__ s2g,
    float* __restrict__ Opart, float* __restrict__ lpart)
{
    __shared__ unsigned short p_lds[2][16][136];   // 2 bufs, row stride 272 B

    const int tid    = threadIdx.x;
    const int bid    = blockIdx.x;
    const int i0     = (bid & 511) * 16;
    const int split  = bid >> 9;               // 0 or 1
    const int jbase  = split * 4096;

    // phase-A layout: 8 row-groups x 32 lanes, 4 adjacent j per lane
    const int lane32 = tid & 31;
    const int rg     = tid >> 5;               // 0..7 -> rows rg, rg+8
    const int jj4    = lane32 * 4;
    const float s1v0 = s1g[i0 + rg];
    const float s1v1 = s1g[i0 + rg + 8];
    float lac0 = 0.f, lac1 = 0.f;

    // MFMA layout: wave w owns output cols n0..n0+15 (out^T: A=WhbT, B=P^T)
    const int l    = tid & 63;
    const int w    = tid >> 6;
    const int n0   = w * 16;
    const int kgrp = l >> 4;
    const unsigned short* Abase = WhbT + (size_t)(n0 + (l & 15)) * NN + jbase + kgrp * 8;
    f32x4 acc = {0.f, 0.f, 0.f, 0.f};

    const int*   ap0 = adj + (size_t)(i0 + rg) * NN + jbase + jj4;
    const int*   ap1 = ap0 + (size_t)8 * NN;
    const float* sp  = s2g + jbase + jj4;

    // prologue: 2-deep prefetch (tiles 0 and 1)
    int4   av0_a = *(const int4*)(ap0);
    int4   av1_a = *(const int4*)(ap1);
    float4 s2_a  = *(const float4*)(sp);
    int4   av0_b = *(const int4*)(ap0 + 128);
    int4   av1_b = *(const int4*)(ap1 + 128);
    float4 s2_b  = *(const float4*)(sp + 128);

#define SC(S1, S2c, M) ((M) ? __expf(fmaxf((S1) + (S2c), ALPHA * ((S1) + (S2c)))) : 0.f)

#define HALF_ITER(T, AV0, AV1, S2V, BUF)  do {                                \
    const int j0 = (T) * 128;                                                 \
    /* A-fragments for this tile (L2-hot; in flight over phase A) */          \
    bf16x8 A0 = *(const bf16x8*)(Abase + j0);                                 \
    bf16x8 A1 = *(const bf16x8*)(Abase + j0 + 32);                            \
    bf16x8 A2 = *(const bf16x8*)(Abase + j0 + 64);                            \
    bf16x8 A3 = *(const bf16x8*)(Abase + j0 + 96);                            \
    /* phase A: 8 scores -> packed bf16 -> LDS buf */                         \
    float p0 = SC(s1v0, S2V.x, AV0.x), p1 = SC(s1v0, S2V.y, AV0.y);           \
    float p2 = SC(s1v0, S2V.z, AV0.z), p3 = SC(s1v0, S2V.w, AV0.w);           \
    float q0 = SC(s1v1, S2V.x, AV1.x), q1 = SC(s1v1, S2V.y, AV1.y);           \
    float q2 = SC(s1v1, S2V.z, AV1.z), q3 = SC(s1v1, S2V.w, AV1.w);           \
    lac0 += (p0 + p1) + (p2 + p3);                                            \
    lac1 += (q0 + q1) + (q2 + q3);                                            \
    uint2 pw, qw;                                                             \
    asm("v_cvt_pk_bf16_f32 %0, %1, %2" : "=v"(pw.x) : "v"(p0), "v"(p1));      \
    asm("v_cvt_pk_bf16_f32 %0, %1, %2" : "=v"(pw.y) : "v"(p2), "v"(p3));      \
    asm("v_cvt_pk_bf16_f32 %0, %1, %2" : "=v"(qw.x) : "v"(q0), "v"(q1));      \
    asm("v_cvt_pk_bf16_f32 %0, %1, %2" : "=v"(qw.y) : "v"(q2), "v"(q3));      \
    *(uint2*)&p_lds[BUF][rg][jj4]     = pw;                                   \
    *(uint2*)&p_lds[BUF][rg + 8][jj4] = qw;                                   \
    /* prefetch tile T+2 into this slot (clamped; extra loads harmless) */    \
    {   const int tn = ((T) + 2 > 31) ? 31 : (T) + 2;                         \
        AV0 = *(const int4*)(ap0 + tn * 128);                                 \
        AV1 = *(const int4*)(ap1 + tn * 128);                                 \
        S2V = *(const float4*)(sp + tn * 128);  }                             \
    __syncthreads();                                                          \
    /* phase B: out^T tile += WhbT-tile * P^T-tile */                         \
    const unsigned short* Bb = &p_lds[BUF][l & 15][kgrp * 8];                 \
    bf16x8 B0 = *(const bf16x8*)(Bb);                                         \
    bf16x8 B1 = *(const bf16x8*)(Bb + 32);                                    \
    bf16x8 B2 = *(const bf16x8*)(Bb + 64);                                    \
    bf16x8 B3 = *(const bf16x8*)(Bb + 96);                                    \
    acc = __builtin_amdgcn_mfma_f32_16x16x32_bf16(A0, B0, acc, 0, 0, 0);      \
    acc = __builtin_amdgcn_mfma_f32_16x16x32_bf16(A1, B1, acc, 0, 0, 0);      \
    acc = __builtin_amdgcn_mfma_f32_16x16x32_bf16(A2, B2, acc, 0, 0, 0);      \
    acc = __builtin_amdgcn_mfma_f32_16x16x32_bf16(A3, B3, acc, 0, 0, 0);      \
} while (0)

    for (int t = 0; t < 32; t += 2) {
        HALF_ITER(t,     av0_a, av1_a, s2_a, 0);
        HALF_ITER(t + 1, av0_b, av1_b, s2_b, 1);
    }
#undef HALF_ITER
#undef SC

    // reduce row-sums over the 32 lanes of each row-group
    #pragma unroll
    for (int m = 16; m; m >>= 1) {
        lac0 += __shfl_xor(lac0, m, 64);
        lac1 += __shfl_xor(lac1, m, 64);
    }
    if (lane32 == 0) {
        lpart[(size_t)split * NN + i0 + rg]     = lac0;
        lpart[(size_t)split * NN + i0 + rg + 8] = lac1;
    }

    // write numerator partial: C layout col=lane&15 (i-local), row=(lane>>4)*4+q (n-local)
    const int ii = l & 15;
    const int nn = (l >> 4) * 4;
    float4 o;
    o.x = acc[0]; o.y = acc[1]; o.z = acc[2]; o.w = acc[3];
    *(float4*)&Opart[((size_t)split * NN + i0 + ii) * OUTF + n0 + nn] = o;
}

// ---------------------------------------------------------------------------
// Kernel 3: combine j-split partials and normalize.
// ---------------------------------------------------------------------------
__global__ __launch_bounds__(256) void k3_combine(
    const float* __restrict__ Opart, const float* __restrict__ lpart,
    float* __restrict__ out)
{
    const int f4 = blockIdx.x * 256 + threadIdx.x;   // 0..131071
    const int i  = f4 >> 4;
    float4 o0 = *(const float4*)&Opart[(size_t)f4 * 4];
    float4 o1 = *(const float4*)&Opart[(size_t)NN * OUTF + (size_t)f4 * 4];
    float inv = 1.0f / (lpart[i] + lpart[NN + i]);
    float4 r;
    r.x = (o0.x + o1.x) * inv;
    r.y = (o0.y + o1.y) * inv;
    r.z = (o0.z + o1.z) * inv;
    r.w = (o0.w + o1.w) * inv;
    *(float4*)&out[(size_t)f4 * 4] = r;
}

extern "C" void kernel_launch(void* const* d_in, const int* in_sizes, int n_in,
                              void* d_out, int out_size, void* d_ws, size_t ws_size,
                              hipStream_t stream) {
    const float* x   = (const float*)d_in[0];
    const int*   adj = (const int*)d_in[1];
    const float* W   = (const float*)d_in[2];
    const float* a   = (const float*)d_in[3];
    float* out = (float*)d_out;

    char* ws = (char*)d_ws;
    unsigned short* WhbT = (unsigned short*)ws;                    // 1 MB
    float* s1    = (float*)(ws + (1 << 20));                       // 32 KB
    float* s2    = (float*)(ws + (1 << 20) + 32768);               // 32 KB
    float* lpart = (float*)(ws + (1 << 20) + 65536);               // 64 KB
    float* Opart = (float*)(ws + (1 << 20) + 65536 + 65536);       // 4 MB

    k1_gemm<<<512, 256, 0, stream>>>(x, W, a, WhbT, s1, s2);
    k2_attn<<<1024, 256, 0, stream>>>(adj, WhbT, s1, s2, Opart, lpart);
    k3_combine<<<512, 256, 0, stream>>>(Opart, lpart, out);
}